// Round 2
// baseline (139.955 us; speedup 1.0000x reference)
//
#include <hip/hip_runtime.h>
#include <hip/hip_bf16.h>
#include <stdint.h>

typedef unsigned short u16;
typedef __attribute__((ext_vector_type(8))) short shortx8;
typedef __attribute__((ext_vector_type(4))) float floatx4;

#define N_ROWS 8192
#define N_COLS 512
#define KDIM   1024

__device__ __forceinline__ u16 f2bf(float f) {
    union { float f; uint32_t u; } x; x.f = f;
    uint32_t u = x.u;
    uint32_t r = (u + 0x7FFFu + ((u >> 16) & 1u)) >> 16;  // RNE
    return (u16)r;
}

__device__ __forceinline__ u16 f2bf_hw(float f) {
    union { __hip_bfloat16 b; u16 u; } x;
    x.b = __float2bfloat16(f);   // hardware RNE cvt (compiler pairs into cvt_pk)
    return x.u;
}

__device__ __forceinline__ void async_copy16(const void* g, void* l) {
    __builtin_amdgcn_global_load_lds(
        (const __attribute__((address_space(1))) void*)g,
        (__attribute__((address_space(3))) void*)l, 16, 0, 0);
}

// ---- kernel 1: protos prep only --------------------------------------------
// 128 blocks: protos->bf16 B[c][k]=(pr||pi) + |p|^2 (wave-per-class).
// Also zeroes d_out (runs before combine's atomics).
__global__ __launch_bounds__(256) void prep(const float* __restrict__ protos,
                                            u16* __restrict__ bb,
                                            float* __restrict__ psq,
                                            float* __restrict__ out) {
    int t = threadIdx.x, lane = t & 63, w = t >> 6;
    if (blockIdx.x == 0 && t == 0) { out[0] = 0.0f; out[1] = 0.0f; }
    int c = blockIdx.x * 4 + w;               // 0..511
    const float4* pr = (const float4*)(protos + (size_t)c * 512);
    const float4* pi = (const float4*)(protos + 512 * 512 + (size_t)c * 512);
    ushort4* dr = (ushort4*)(bb + (size_t)c * KDIM);
    ushort4* di = (ushort4*)(bb + (size_t)c * KDIM + 512);
    float s = 0.0f;
    #pragma unroll
    for (int j = 0; j < 2; j++) {
        float4 a = pr[lane + j * 64];
        float4 b = pi[lane + j * 64];
        s += a.x * a.x + a.y * a.y + a.z * a.z + a.w * a.w;
        s += b.x * b.x + b.y * b.y + b.z * b.z + b.w * b.w;
        dr[lane + j * 64] = make_ushort4(f2bf(a.x), f2bf(a.y), f2bf(a.z), f2bf(a.w));
        di[lane + j * 64] = make_ushort4(f2bf(b.x), f2bf(b.y), f2bf(b.z), f2bf(b.w));
    }
    #pragma unroll
    for (int off = 32; off; off >>= 1) s += __shfl_xor(s, off);
    if (lane == 0) psq[c] = s;
}

// ---- kernel 2: fused cvt + bf16 MFMA GEMM + logits + row-partials ----------
// BM=128, BN=64, BK=64, 256 threads (4 waves, each 64x32), 512 blocks 1D.
// A is staged from fp32 h directly: global->reg (prefetched across the MFMA
// phase) -> cvt bf16 + hsq fma -> swizzled ds_write. Removes the 16 MiB hb
// round trip and the whole conv kernel. B (bb) double-buffered via
// global_load_lds. hsq computed in-kernel (redundantly per column-block).
__global__ __launch_bounds__(256) void gemm_fused(const float* __restrict__ h,
                                                  const u16* __restrict__ bb,
                                                  const float* __restrict__ psq,
                                                  const float* __restrict__ radii,
                                                  const int* __restrict__ y,
                                                  const int* __restrict__ slab,
                                                  const int* __restrict__ ninit_p,
                                                  float* __restrict__ pmax_g,
                                                  int* __restrict__ pidx_g,
                                                  float* __restrict__ prmax_g,
                                                  float* __restrict__ pc0_g,
                                                  float* __restrict__ psum_g,
                                                  float* __restrict__ l0arr) {
    constexpr int BM = 128, BN = 64, BK = 64, NSTEP = KDIM / BK;
    __shared__ __align__(16) u16 As[BM * BK];      // 16 KiB
    __shared__ __align__(16) u16 Bs[2][BN * BK];   // 2 x 8 KiB
    __shared__ float shsq[BM];
    __shared__ float smax[2][128];
    __shared__ int   scol[2][128];
    __shared__ float srmx[2][128];
    __shared__ float sc0v[2][128];
    __shared__ float ssum[2][128];

    int t = threadIdx.x, lane = t & 63, w = t >> 6;
    int wr = (w & 1) * 64;          // wave row offset
    int wc = (w >> 1) * 32;         // wave col offset

    // XCD swizzle (bijective, 512 % 8 == 0): 8 col-blocks of one A panel on
    // one XCD -> fp32 panel (512 KB) + bb (1 MB) L2-resident per XCD.
    int bid = blockIdx.x;
    int xcd = bid & 7;
    int idin = bid >> 3;
    int bx = (xcd << 3) | (idin >> 3);
    int by = idin & 7;
    int bm0 = bx * BM;
    int bn0 = by * BN;

    // A staging: thread t owns row arow = t>>1, k-half ahalf = t&1
    // (32 contiguous floats = 8 float4 per K-step).
    int arow = t >> 1, ahalf = t & 1;
    const float4* gA = (const float4*)(h + (size_t)(bm0 + arow) * KDIM + ahalf * 32);
    // LDS write targets: global kchunk kcg stored at position kcg ^ (arow&7)
    // (same layout the ds_read side expects; constant across steps).
    u16* lAw[4];
    #pragma unroll
    for (int j = 0; j < 4; j++) {
        int kcg = ahalf * 4 + j;
        lAw[j] = &As[arow * BK + ((kcg ^ (arow & 7)) * 8)];
    }

    // B staging via global_load_lds (bf16, pre-swizzled global addr).
    int tr = t >> 3, tc = t & 7;
    const u16* gB[2];
    int lBoff[2];
    #pragma unroll
    for (int i = 0; i < 2; i++) {
        int row = tr + 32 * i;
        int kc = tc ^ (row & 7);
        gB[i] = bb + (size_t)(bn0 + row) * KDIM + kc * 8;
        lBoff[i] = (t + 256 * i) * 8;
    }

    floatx4 acc[4][2] = {};
    int kq = lane >> 4, l7 = lane & 7, m = lane & 15;
    int swz0 = ((kq) ^ l7) * 8;
    int swz1 = ((4 + kq) ^ l7) * 8;
    const u16* paA = &As[(wr + m) * BK];

    float hs = 0.0f;
    float4 av[8];

    // prologue: tile 0 in flight
    #pragma unroll
    for (int j = 0; j < 8; j++) av[j] = gA[j];
    #pragma unroll
    for (int i = 0; i < 2; i++) async_copy16(gB[i], &Bs[0][lBoff[i]]);

    for (int step = 0; step < NSTEP; ++step) {
        __syncthreads();                       // all waves done reading As(step-1)
        // cvt fp32->bf16 + hsq fma + swizzled LDS write
        #pragma unroll
        for (int j = 0; j < 4; j++) {
            float4 a = av[2 * j], b = av[2 * j + 1];
            hs += a.x * a.x + a.y * a.y + a.z * a.z + a.w * a.w
                + b.x * b.x + b.y * b.y + b.z * b.z + b.w * b.w;
            shortx8 p;
            p[0] = (short)f2bf_hw(a.x); p[1] = (short)f2bf_hw(a.y);
            p[2] = (short)f2bf_hw(a.z); p[3] = (short)f2bf_hw(a.w);
            p[4] = (short)f2bf_hw(b.x); p[5] = (short)f2bf_hw(b.y);
            p[6] = (short)f2bf_hw(b.z); p[7] = (short)f2bf_hw(b.w);
            *(shortx8*)lAw[j] = p;
        }
        __syncthreads();                       // As(step), Bs[step&1] ready
        if (step + 1 < NSTEP) {                // prefetch under the MFMA phase
            const float4* gAn = gA + (step + 1) * 16;
            #pragma unroll
            for (int j = 0; j < 8; j++) av[j] = gAn[j];
            #pragma unroll
            for (int i = 0; i < 2; i++)
                async_copy16(gB[i] + (size_t)(step + 1) * BK, &Bs[(step + 1) & 1][lBoff[i]]);
        }
        const u16* paB = &Bs[step & 1][(wc + m) * BK];
        #pragma unroll
        for (int s = 0; s < 2; s++) {
            int sw = s ? swz1 : swz0;
            shortx8 af[4], bf[2];
            #pragma unroll
            for (int i = 0; i < 4; i++) af[i] = *(const shortx8*)(paA + i * 16 * BK + sw);
            #pragma unroll
            for (int jj = 0; jj < 2; jj++) bf[jj] = *(const shortx8*)(paB + jj * 16 * BK + sw);
            #pragma unroll
            for (int i = 0; i < 4; i++)
                #pragma unroll
                for (int jj = 0; jj < 2; jj++)
                    acc[i][jj] = __builtin_amdgcn_mfma_f32_16x16x32_bf16(af[i], bf[jj], acc[i][jj], 0, 0, 0);
        }
    }

    // finalize hsq: thread-pair (row, half0/half1) -> full row sum
    hs += __shfl_xor(hs, 1);
    if (ahalf == 0) shsq[arow] = hs;
    __syncthreads();

    // ---- epilogue: logits in-register, reduce 64 cols -> per-row partials --
    // C/D: col = lane&15 (=m), row = kq*4 + reg. Lane's 2 cols:
    int c0 = bn0 + wc + m, c1 = c0 + 16;
    float ps0 = psq[c0], ps1 = psq[c1];
    float inv0 = 0.5f / radii[c0], inv1 = 0.5f / radii[c1];
    int sl0 = slab[c0], sl1 = slab[c1];
    int slabz = slab[0];
    int ninit = ninit_p[0];
    int ch = w >> 1;                 // column half within block
    bool isL0 = (bn0 == 0) && (wc == 0) && (m == 0);

    #pragma unroll
    for (int i = 0; i < 4; i++) {
        #pragma unroll
        for (int r = 0; r < 4; r++) {
            int lr = wr + i * 16 + kq * 4 + r;
            int n = bm0 + lr;
            float hsqn = shsq[lr];
            int yv = y[n];
            int lab = (yv >= ninit) ? -1 : yv;
            float v0 = (2.0f * acc[i][0][r] - hsqn - ps0) * inv0;
            float v1 = (2.0f * acc[i][1][r] - hsqn - ps1) * inv1;
            if (isL0) l0arr[n] = v0;                 // logits[n][0]

            float bmax = v0; int bcol = c0;
            if (v1 > bmax) { bmax = v1; bcol = c1; } // tie keeps lower col
            float brm = -INFINITY;
            if (sl0 == lab) brm = v0;
            if (sl1 == lab && v1 > brm) brm = v1;
            float bc0 = -INFINITY;
            if (sl0 == slabz) bc0 = v0;
            if (sl1 == slabz && v1 > bc0) bc0 = v1;
            #pragma unroll
            for (int off = 1; off < 16; off <<= 1) {   // reduce over m (16 lanes)
                float ov = __shfl_xor(bmax, off); int oc = __shfl_xor(bcol, off);
                if (ov > bmax || (ov == bmax && oc < bcol)) { bmax = ov; bcol = oc; }
                float orv = __shfl_xor(brm, off); if (orv > brm) brm = orv;
                float oc0 = __shfl_xor(bc0, off); if (oc0 > bc0) bc0 = oc0;
            }
            float se = __expf(v0 - bmax) + __expf(v1 - bmax);
            #pragma unroll
            for (int off = 1; off < 16; off <<= 1) se += __shfl_xor(se, off);
            if (m == 0) {
                int rl = (w & 1) * 64 + i * 16 + kq * 4 + r;
                smax[ch][rl] = bmax; scol[ch][rl] = bcol;
                srmx[ch][rl] = brm;  sc0v[ch][rl] = bc0; ssum[ch][rl] = se;
            }
        }
    }
    __syncthreads();
    if (t < 128) {                    // merge the two 32-col halves, write
        int n = bm0 + t;
        size_t gi_ = (size_t)by * N_ROWS + n;
        float m0 = smax[0][t], m1 = smax[1][t];
        int i0 = scol[0][t], i1 = scol[1][t];
        float gm; int gi;
        if (m0 > m1 || (m0 == m1 && i0 < i1)) { gm = m0; gi = i0; }
        else { gm = m1; gi = i1; }
        pmax_g[gi_] = gm;
        pidx_g[gi_] = gi;
        prmax_g[gi_] = fmaxf(srmx[0][t], srmx[1][t]);
        pc0_g[gi_]  = fmaxf(sc0v[0][t], sc0v[1][t]);
        psum_g[gi_] = ssum[0][t] * __expf(m0 - gm) + ssum[1][t] * __expf(m1 - gm);
    }
}

// ---- kernel 3: combine 8 column-block partials per row -> loss, acc --------
__global__ __launch_bounds__(256) void combine(const float* __restrict__ pmax_g,
                                               const int* __restrict__ pidx_g,
                                               const float* __restrict__ prmax_g,
                                               const float* __restrict__ pc0_g,
                                               const float* __restrict__ psum_g,
                                               const float* __restrict__ l0arr,
                                               const int* __restrict__ y,
                                               const int* __restrict__ slab,
                                               const int* __restrict__ ninit_p,
                                               float* __restrict__ out) {
    int t = threadIdx.x, lane = t & 63, w = t >> 6;
    int n = blockIdx.x * 256 + t;

    float gm = -INFINITY; int gi = 0x7fffffff;
    float rm = -INFINITY, c0m = -INFINITY;
    float pm[8];
    #pragma unroll
    for (int cb = 0; cb < 8; cb++) {
        size_t idx = (size_t)cb * N_ROWS + n;
        float p = pmax_g[idx]; int pi = pidx_g[idx];
        pm[cb] = p;
        if (p > gm || (p == gm && pi < gi)) { gm = p; gi = pi; }
        rm = fmaxf(rm, prmax_g[idx]);
        c0m = fmaxf(c0m, pc0_g[idx]);
    }
    float den = 0.0f;
    #pragma unroll
    for (int cb = 0; cb < 8; cb++)
        den += psum_g[(size_t)cb * N_ROWS + n] * __expf(pm[cb] - gm);
    float lse = gm + __logf(den);

    int yv = y[n];
    int lab = (yv >= ninit_p[0]) ? -1 : yv;
    float nll, wgt;
    if (rm != -INFINITY) { nll = lse - rm; wgt = 1.0f; }
    else {                                   // all-(-inf) argmax -> col 0
        float l0 = l0arr[n];
        nll = lse - l0;
        wgt = (l0 == c0m) ? 1.0f : 0.0f;
    }
    int ypred = slab[gi];
    float li = nll * wgt * (1.0f / (float)N_ROWS);
    float ai = (ypred == lab) ? 1.0f : 0.0f;

    #pragma unroll
    for (int off = 32; off; off >>= 1) {
        li += __shfl_xor(li, off);
        ai += __shfl_xor(ai, off);
    }
    __shared__ float pl[4], pa_[4];
    if (lane == 0) { pl[w] = li; pa_[w] = ai; }
    __syncthreads();
    if (t == 0) {
        atomicAdd(&out[0], pl[0] + pl[1] + pl[2] + pl[3]);
        atomicAdd(&out[1], pa_[0] + pa_[1] + pa_[2] + pa_[3]);
    }
}

extern "C" void kernel_launch(void* const* d_in, const int* in_sizes, int n_in,
                              void* d_out, int out_size, void* d_ws, size_t ws_size,
                              hipStream_t stream) {
    const float* h      = (const float*)d_in[0];
    const float* protos = (const float*)d_in[1];
    const float* radii  = (const float*)d_in[2];
    const int*   y      = (const int*)d_in[3];
    const int*   slab   = (const int*)d_in[4];
    const int*   ninit  = (const int*)d_in[5];
    float* out = (float*)d_out;

    char* ws = (char*)d_ws;
    u16*   bb    = (u16*)(ws + 16777216);            // 1 MiB
    float* pmax  = (float*)(ws + 17860608);          // 8*8192*4 = 256 KiB
    int*   pidx  = (int*)  (ws + 18122752);
    float* prmax = (float*)(ws + 18384896);
    float* pc0   = (float*)(ws + 18647040);
    float* psum  = (float*)(ws + 18909184);
    float* l0arr = (float*)(ws + 19171328);          // 32 KiB
    float* psq   = (float*)(ws + 17858560);          // 2 KiB

    prep<<<128, 256, 0, stream>>>(protos, bb, psq, out);
    gemm_fused<<<512, 256, 0, stream>>>(h, bb, psq, radii, y, slab, ninit,
                                        pmax, pidx, prmax, pc0, psum, l0arr);
    combine<<<N_ROWS / 256, 256, 0, stream>>>(pmax, pidx, prmax, pc0, psum,
                                              l0arr, y, slab, ninit, out);
}

// Round 3
// 123.744 us; speedup vs baseline: 1.1310x; 1.1310x over previous
//
#include <hip/hip_runtime.h>
#include <hip/hip_bf16.h>
#include <stdint.h>

typedef unsigned short u16;
typedef __attribute__((ext_vector_type(8))) short shortx8;
typedef __attribute__((ext_vector_type(4))) float floatx4;

#define N_ROWS 8192
#define N_COLS 512
#define KDIM   1024

__device__ __forceinline__ u16 f2bf(float f) {
    union { float f; uint32_t u; } x; x.f = f;
    uint32_t u = x.u;
    uint32_t r = (u + 0x7FFFu + ((u >> 16) & 1u)) >> 16;  // RNE
    return (u16)r;
}

__device__ __forceinline__ u16 f2bf_hw(float f) {
    union { __hip_bfloat16 b; u16 u; } x;
    x.b = __float2bfloat16(f);   // hardware RNE cvt (compiler packs into cvt_pk)
    return x.u;
}

__device__ __forceinline__ void async_copy16(const void* g, void* l) {
    __builtin_amdgcn_global_load_lds(
        (const __attribute__((address_space(1))) void*)g,
        (__attribute__((address_space(3))) void*)l, 16, 0, 0);
}

// ---- kernel 1: protos prep only --------------------------------------------
// 128 blocks: protos->bf16 B[c][k]=(pr||pi) + |p|^2 (wave-per-class).
// Also zeroes d_out (runs before combine's atomics).
__global__ __launch_bounds__(256) void prep(const float* __restrict__ protos,
                                            u16* __restrict__ bb,
                                            float* __restrict__ psq,
                                            float* __restrict__ out) {
    int t = threadIdx.x, lane = t & 63, w = t >> 6;
    if (blockIdx.x == 0 && t == 0) { out[0] = 0.0f; out[1] = 0.0f; }
    int c = blockIdx.x * 4 + w;               // 0..511
    const float4* pr = (const float4*)(protos + (size_t)c * 512);
    const float4* pi = (const float4*)(protos + 512 * 512 + (size_t)c * 512);
    ushort4* dr = (ushort4*)(bb + (size_t)c * KDIM);
    ushort4* di = (ushort4*)(bb + (size_t)c * KDIM + 512);
    float s = 0.0f;
    #pragma unroll
    for (int j = 0; j < 2; j++) {
        float4 a = pr[lane + j * 64];
        float4 b = pi[lane + j * 64];
        s += a.x * a.x + a.y * a.y + a.z * a.z + a.w * a.w;
        s += b.x * b.x + b.y * b.y + b.z * b.z + b.w * b.w;
        dr[lane + j * 64] = make_ushort4(f2bf(a.x), f2bf(a.y), f2bf(a.z), f2bf(a.w));
        di[lane + j * 64] = make_ushort4(f2bf(b.x), f2bf(b.y), f2bf(b.z), f2bf(b.w));
    }
    #pragma unroll
    for (int off = 32; off; off >>= 1) s += __shfl_xor(s, off);
    if (lane == 0) psq[c] = s;
}

// ---- kernel 2: fused cvt + bf16 MFMA GEMM + logits + row-partials ----------
// BM=128, BN=64, BK=64, 256 threads (4 waves each 64x32), 512 blocks.
// A path: coalesced slot-based global fp32 loads (thread t, chunk q reads the
// 16B chunk at flat slot q*256+t: lanes 16B apart) -> register cvt ->
// ds_write_b64 into the SAME swizzled bf16 As layout round-1's verified MFMA
// read path expects (chunk c of row r at position c^(r&7)). hsq accumulated
// in-register from the fp32 values (exact), reduced via 16-lane shuffles.
// B: bf16 via global_load_lds, double-buffered (unchanged from round-1).
__global__ __launch_bounds__(256, 2) void gemm_fused(const float* __restrict__ h,
                                                     const u16* __restrict__ bb,
                                                     const float* __restrict__ psq,
                                                     const float* __restrict__ radii,
                                                     const int* __restrict__ y,
                                                     const int* __restrict__ slab,
                                                     const int* __restrict__ ninit_p,
                                                     float* __restrict__ pmax_g,
                                                     int* __restrict__ pidx_g,
                                                     float* __restrict__ prmax_g,
                                                     float* __restrict__ pc0_g,
                                                     float* __restrict__ psum_g,
                                                     float* __restrict__ l0arr) {
    constexpr int BM = 128, BN = 64, BK = 64, NSTEP = KDIM / BK;
    __shared__ __align__(16) u16 As[BM * BK];      // 16 KiB
    __shared__ __align__(16) u16 Bs[2][BN * BK];   // 2 x 8 KiB
    __shared__ float shsq[BM];
    __shared__ float smax[2][128];
    __shared__ int   scol[2][128];
    __shared__ float srmx[2][128];
    __shared__ float sc0v[2][128];
    __shared__ float ssum[2][128];

    int t = threadIdx.x, lane = t & 63, w = t >> 6;
    int wr = (w & 1) * 64;          // wave row offset
    int wc = (w >> 1) * 32;         // wave col offset

    // XCD swizzle (bijective, 512 % 8 == 0)
    int bid = blockIdx.x;
    int xcd = bid & 7;
    int idin = bid >> 3;
    int bx = (xcd << 3) | (idin >> 3);
    int by = idin & 7;
    int bm0 = bx * BM;
    int bn0 = by * BN;

    // A staging geometry: slot (q, t): row = q*16 + (t>>4), fp32-chunk = t&15.
    int arow4 = t >> 4;             // 0..15
    int apos  = t & 15;             // 16B fp32 chunk within row (16 chunks)
    const float* gA0 = h + (size_t)(bm0 + arow4) * KDIM + apos * 4;
    // bf16 As write: 16B-bf16-chunk kc = apos>>1, half = apos&1,
    // stored at position kc ^ (r&7); r&7 == arow4&7 (q*16 is 0 mod 8).
    int swzA = ((apos >> 1) ^ (arow4 & 7));
    u16* pAsW = &As[arow4 * 64 + swzA * 8 + (apos & 1) * 4];  // + q*1024

    // B staging via global_load_lds (pre-swizzled global addr) — round-1 code.
    int tr = t >> 3, tc = t & 7;
    const u16* gB[2];
    int lBoff[2];
    #pragma unroll
    for (int i = 0; i < 2; i++) {
        int row = tr + 32 * i;
        int kc = tc ^ (row & 7);
        gB[i] = bb + (size_t)(bn0 + row) * KDIM + kc * 8;
        lBoff[i] = (t + 256 * i) * 8;
    }

    floatx4 acc[4][2] = {};
    int kq = lane >> 4, l7 = lane & 7, m = lane & 15;
    int swz0 = ((kq) ^ l7) * 8;
    int swz1 = ((4 + kq) ^ l7) * 8;
    const u16* paA = &As[(wr + m) * BK];

    float hs[8] = {0, 0, 0, 0, 0, 0, 0, 0};
    float4 av[8];

    // ---- prologue: stage tile 0 -------------------------------------------
    #pragma unroll
    for (int q = 0; q < 8; q++) av[q] = *(const float4*)(gA0 + (size_t)q * 16 * KDIM);
    #pragma unroll
    for (int i = 0; i < 2; i++) async_copy16(gB[i], &Bs[0][lBoff[i]]);
    #pragma unroll
    for (int q = 0; q < 8; q++) {
        float4 v = av[q];
        hs[q] += v.x * v.x + v.y * v.y + v.z * v.z + v.w * v.w;
        *(ushort4*)(pAsW + q * 1024) =
            make_ushort4(f2bf_hw(v.x), f2bf_hw(v.y), f2bf_hw(v.z), f2bf_hw(v.w));
    }
    __syncthreads();

    // ---- main loop ---------------------------------------------------------
    for (int step = 0; step < NSTEP; ++step) {
        if (step + 1 < NSTEP) {      // issue next-tile loads; fly under MFMA
            const float* gAn = gA0 + (step + 1) * 64;
            #pragma unroll
            for (int q = 0; q < 8; q++) av[q] = *(const float4*)(gAn + (size_t)q * 16 * KDIM);
            #pragma unroll
            for (int i = 0; i < 2; i++)
                async_copy16(gB[i] + (size_t)(step + 1) * BK, &Bs[(step + 1) & 1][lBoff[i]]);
        }
        // fragment reads + MFMA (round-1 verified path)
        const u16* paB = &Bs[step & 1][(wc + m) * BK];
        #pragma unroll
        for (int s = 0; s < 2; s++) {
            int sw = s ? swz1 : swz0;
            shortx8 af[4], bf[2];
            #pragma unroll
            for (int i = 0; i < 4; i++) af[i] = *(const shortx8*)(paA + i * 16 * BK + sw);
            #pragma unroll
            for (int jj = 0; jj < 2; jj++) bf[jj] = *(const shortx8*)(paB + jj * 16 * BK + sw);
            #pragma unroll
            for (int i = 0; i < 4; i++)
                #pragma unroll
                for (int jj = 0; jj < 2; jj++)
                    acc[i][jj] = __builtin_amdgcn_mfma_f32_16x16x32_bf16(af[i], bf[jj], acc[i][jj], 0, 0, 0);
        }
        if (step + 1 < NSTEP) {
            __syncthreads();         // all waves done reading As(step); av landed
            #pragma unroll
            for (int q = 0; q < 8; q++) {
                float4 v = av[q];
                hs[q] += v.x * v.x + v.y * v.y + v.z * v.z + v.w * v.w;
                *(ushort4*)(pAsW + q * 1024) =
                    make_ushort4(f2bf_hw(v.x), f2bf_hw(v.y), f2bf_hw(v.z), f2bf_hw(v.w));
            }
            __syncthreads();         // As(step+1) ready
        }
    }

    // ---- finalize hsq: reduce each row's 16 chunk-partials -----------------
    #pragma unroll
    for (int q = 0; q < 8; q++) {
        float v = hs[q];
        v += __shfl_xor(v, 1);
        v += __shfl_xor(v, 2);
        v += __shfl_xor(v, 4);
        v += __shfl_xor(v, 8);
        if ((t & 15) == 0) shsq[q * 16 + arow4] = v;
    }
    __syncthreads();

    // ---- epilogue: logits in-register, reduce 64 cols -> per-row partials --
    // C/D: col = lane&15 (=m), row = kq*4 + reg. Lane's 2 cols:
    int c0 = bn0 + wc + m, c1 = c0 + 16;
    float ps0 = psq[c0], ps1 = psq[c1];
    float inv0 = 0.5f / radii[c0], inv1 = 0.5f / radii[c1];
    int sl0 = slab[c0], sl1 = slab[c1];
    int slabz = slab[0];
    int ninit = ninit_p[0];
    int ch = w >> 1;                 // column half within block
    bool isL0 = (bn0 == 0) && (wc == 0) && (m == 0);

    #pragma unroll
    for (int i = 0; i < 4; i++) {
        #pragma unroll
        for (int r = 0; r < 4; r++) {
            int lr = wr + i * 16 + kq * 4 + r;
            int n = bm0 + lr;
            float hsqn = shsq[lr];
            int yv = y[n];
            int lab = (yv >= ninit) ? -1 : yv;
            float v0 = (2.0f * acc[i][0][r] - hsqn - ps0) * inv0;
            float v1 = (2.0f * acc[i][1][r] - hsqn - ps1) * inv1;
            if (isL0) l0arr[n] = v0;                 // logits[n][0]

            float bmax = v0; int bcol = c0;
            if (v1 > bmax) { bmax = v1; bcol = c1; } // tie keeps lower col
            float brm = -INFINITY;
            if (sl0 == lab) brm = v0;
            if (sl1 == lab && v1 > brm) brm = v1;
            float bc0 = -INFINITY;
            if (sl0 == slabz) bc0 = v0;
            if (sl1 == slabz && v1 > bc0) bc0 = v1;
            #pragma unroll
            for (int off = 1; off < 16; off <<= 1) {   // reduce over m (16 lanes)
                float ov = __shfl_xor(bmax, off); int oc = __shfl_xor(bcol, off);
                if (ov > bmax || (ov == bmax && oc < bcol)) { bmax = ov; bcol = oc; }
                float orv = __shfl_xor(brm, off); if (orv > brm) brm = orv;
                float oc0 = __shfl_xor(bc0, off); if (oc0 > bc0) bc0 = oc0;
            }
            float se = __expf(v0 - bmax) + __expf(v1 - bmax);
            #pragma unroll
            for (int off = 1; off < 16; off <<= 1) se += __shfl_xor(se, off);
            if (m == 0) {
                int rl = (w & 1) * 64 + i * 16 + kq * 4 + r;
                smax[ch][rl] = bmax; scol[ch][rl] = bcol;
                srmx[ch][rl] = brm;  sc0v[ch][rl] = bc0; ssum[ch][rl] = se;
            }
        }
    }
    __syncthreads();
    if (t < 128) {                    // merge the two 32-col halves, write
        int n = bm0 + t;
        size_t gi_ = (size_t)by * N_ROWS + n;
        float m0 = smax[0][t], m1 = smax[1][t];
        int i0 = scol[0][t], i1 = scol[1][t];
        float gm; int gi;
        if (m0 > m1 || (m0 == m1 && i0 < i1)) { gm = m0; gi = i0; }
        else { gm = m1; gi = i1; }
        pmax_g[gi_] = gm;
        pidx_g[gi_] = gi;
        prmax_g[gi_] = fmaxf(srmx[0][t], srmx[1][t]);
        pc0_g[gi_]  = fmaxf(sc0v[0][t], sc0v[1][t]);
        psum_g[gi_] = ssum[0][t] * __expf(m0 - gm) + ssum[1][t] * __expf(m1 - gm);
    }
}

// ---- kernel 3: combine 8 column-block partials per row -> loss, acc --------
__global__ __launch_bounds__(256) void combine(const float* __restrict__ pmax_g,
                                               const int* __restrict__ pidx_g,
                                               const float* __restrict__ prmax_g,
                                               const float* __restrict__ pc0_g,
                                               const float* __restrict__ psum_g,
                                               const float* __restrict__ l0arr,
                                               const int* __restrict__ y,
                                               const int* __restrict__ slab,
                                               const int* __restrict__ ninit_p,
                                               float* __restrict__ out) {
    int t = threadIdx.x, lane = t & 63, w = t >> 6;
    int n = blockIdx.x * 256 + t;

    float gm = -INFINITY; int gi = 0x7fffffff;
    float rm = -INFINITY, c0m = -INFINITY;
    float pm[8];
    #pragma unroll
    for (int cb = 0; cb < 8; cb++) {
        size_t idx = (size_t)cb * N_ROWS + n;
        float p = pmax_g[idx]; int pi = pidx_g[idx];
        pm[cb] = p;
        if (p > gm || (p == gm && pi < gi)) { gm = p; gi = pi; }
        rm = fmaxf(rm, prmax_g[idx]);
        c0m = fmaxf(c0m, pc0_g[idx]);
    }
    float den = 0.0f;
    #pragma unroll
    for (int cb = 0; cb < 8; cb++)
        den += psum_g[(size_t)cb * N_ROWS + n] * __expf(pm[cb] - gm);
    float lse = gm + __logf(den);

    int yv = y[n];
    int lab = (yv >= ninit_p[0]) ? -1 : yv;
    float nll, wgt;
    if (rm != -INFINITY) { nll = lse - rm; wgt = 1.0f; }
    else {                                   // all-(-inf) argmax -> col 0
        float l0 = l0arr[n];
        nll = lse - l0;
        wgt = (l0 == c0m) ? 1.0f : 0.0f;
    }
    int ypred = slab[gi];
    float li = nll * wgt * (1.0f / (float)N_ROWS);
    float ai = (ypred == lab) ? 1.0f : 0.0f;

    #pragma unroll
    for (int off = 32; off; off >>= 1) {
        li += __shfl_xor(li, off);
        ai += __shfl_xor(ai, off);
    }
    __shared__ float pl[4], pa_[4];
    if (lane == 0) { pl[w] = li; pa_[w] = ai; }
    __syncthreads();
    if (t == 0) {
        atomicAdd(&out[0], pl[0] + pl[1] + pl[2] + pl[3]);
        atomicAdd(&out[1], pa_[0] + pa_[1] + pa_[2] + pa_[3]);
    }
}

extern "C" void kernel_launch(void* const* d_in, const int* in_sizes, int n_in,
                              void* d_out, int out_size, void* d_ws, size_t ws_size,
                              hipStream_t stream) {
    const float* h      = (const float*)d_in[0];
    const float* protos = (const float*)d_in[1];
    const float* radii  = (const float*)d_in[2];
    const int*   y      = (const int*)d_in[3];
    const int*   slab   = (const int*)d_in[4];
    const int*   ninit  = (const int*)d_in[5];
    float* out = (float*)d_out;

    char* ws = (char*)d_ws;
    u16*   bb    = (u16*)(ws + 16777216);            // 1 MiB
    float* psq   = (float*)(ws + 17858560);          // 2 KiB
    float* pmax  = (float*)(ws + 17860608);          // 8*8192*4 = 256 KiB
    int*   pidx  = (int*)  (ws + 18122752);
    float* prmax = (float*)(ws + 18384896);
    float* pc0   = (float*)(ws + 18647040);
    float* psum  = (float*)(ws + 18909184);
    float* l0arr = (float*)(ws + 19171328);          // 32 KiB

    prep<<<128, 256, 0, stream>>>(protos, bb, psq, out);
    gemm_fused<<<512, 256, 0, stream>>>(h, bb, psq, radii, y, slab, ninit,
                                        pmax, pidx, prmax, pc0, psum, l0arr);
    combine<<<N_ROWS / 256, 256, 0, stream>>>(pmax, pidx, prmax, pc0, psum,
                                              l0arr, y, slab, ninit, out);
}

// Round 4
// 119.955 us; speedup vs baseline: 1.1667x; 1.0316x over previous
//
#include <hip/hip_runtime.h>
#include <stdint.h>

typedef unsigned short u16;
typedef __attribute__((ext_vector_type(8))) short shortx8;
typedef __attribute__((ext_vector_type(4))) float floatx4;

#define N_ROWS 8192
#define N_COLS 512
#define KDIM   1024

__device__ __forceinline__ u16 f2bf(float f) {
    union { float f; uint32_t u; } x; x.f = f;
    uint32_t u = x.u;
    uint32_t r = (u + 0x7FFFu + ((u >> 16) & 1u)) >> 16;  // RNE
    return (u16)r;
}

__device__ __forceinline__ void async_copy16(const void* g, void* l) {
    __builtin_amdgcn_global_load_lds(
        (const __attribute__((address_space(1))) void*)g,
        (__attribute__((address_space(3))) void*)l, 16, 0, 0);
}

// ---- kernel 1: fused input prep --------------------------------------------
// blocks [0,512): h fp32->bf16 + row |h|^2 (wave-per-row, 4 rows/wave)
// blocks [512,640): protos->bf16 B[c][k]=(pr||pi) + |p|^2 (wave-per-class)
// Also zeroes d_out (runs before combine's atomics; saves a memset dispatch).
__global__ __launch_bounds__(256) void conv_hp(const float* __restrict__ h,
                                               const float* __restrict__ protos,
                                               u16* __restrict__ hb,
                                               u16* __restrict__ bb,
                                               float* __restrict__ hsq,
                                               float* __restrict__ psq,
                                               float* __restrict__ out) {
    int t = threadIdx.x, lane = t & 63, w = t >> 6;
    int bid = blockIdx.x;
    if (bid == 0 && t == 0) { out[0] = 0.0f; out[1] = 0.0f; }
    if (bid < 512) {
        int wave = bid * 4 + w;                    // 0..2047
        for (int q = 0; q < 4; q++) {
            int row = wave * 4 + q;
            const float4* src = (const float4*)(h + (size_t)row * KDIM);
            ushort4* dst = (ushort4*)(hb + (size_t)row * KDIM);
            float s = 0.0f;
            #pragma unroll
            for (int j = 0; j < 4; j++) {
                float4 v = src[lane + j * 64];
                s += v.x * v.x + v.y * v.y + v.z * v.z + v.w * v.w;
                dst[lane + j * 64] = make_ushort4(f2bf(v.x), f2bf(v.y), f2bf(v.z), f2bf(v.w));
            }
            #pragma unroll
            for (int off = 32; off; off >>= 1) s += __shfl_xor(s, off);
            if (lane == 0) hsq[row] = s;
        }
    } else {
        int c = (bid - 512) * 4 + w;               // 0..511
        const float4* pr = (const float4*)(protos + (size_t)c * 512);
        const float4* pi = (const float4*)(protos + 512 * 512 + (size_t)c * 512);
        ushort4* dr = (ushort4*)(bb + (size_t)c * KDIM);
        ushort4* di = (ushort4*)(bb + (size_t)c * KDIM + 512);
        float s = 0.0f;
        #pragma unroll
        for (int j = 0; j < 2; j++) {
            float4 a = pr[lane + j * 64];
            float4 b = pi[lane + j * 64];
            s += a.x * a.x + a.y * a.y + a.z * a.z + a.w * a.w;
            s += b.x * b.x + b.y * b.y + b.z * b.z + b.w * b.w;
            dr[lane + j * 64] = make_ushort4(f2bf(a.x), f2bf(a.y), f2bf(a.z), f2bf(a.w));
            di[lane + j * 64] = make_ushort4(f2bf(b.x), f2bf(b.y), f2bf(b.z), f2bf(b.w));
        }
        #pragma unroll
        for (int off = 32; off; off >>= 1) s += __shfl_xor(s, off);
        if (lane == 0) psq[c] = s;
    }
}

// ---- kernel 2: bf16 MFMA GEMM + fused logits + row-partial reduction -------
// BM=128, BN=64, BK=64, 256 threads (4 waves each 64x32), 512 blocks.
// 2-phase double-buffered K-loop (T3-minimum): stage tile t+1 into buf^1,
// THEN ds_read+MFMA tile t, then ONE barrier per step — the prefetch is in
// flight across the whole compute phase instead of being drained immediately
// (round-1 exposed full load latency at a second barrier every step).
// Fragment-read path and epilogue identical to the verified round-1 code.
__global__ __launch_bounds__(256) void gemm_partials(const u16* __restrict__ hb,
                                                     const u16* __restrict__ bb,
                                                     const float* __restrict__ hsq,
                                                     const float* __restrict__ psq,
                                                     const float* __restrict__ radii,
                                                     const int* __restrict__ y,
                                                     const int* __restrict__ slab,
                                                     const int* __restrict__ ninit_p,
                                                     float* __restrict__ pmax_g,
                                                     int* __restrict__ pidx_g,
                                                     float* __restrict__ prmax_g,
                                                     float* __restrict__ pc0_g,
                                                     float* __restrict__ psum_g,
                                                     float* __restrict__ l0arr) {
    constexpr int BM = 128, BN = 64, BK = 64, NSTEP = KDIM / BK;
    __shared__ __align__(16) u16 As[2][BM * BK];   // 2 x 16 KiB
    __shared__ __align__(16) u16 Bs[2][BN * BK];   // 2 x 8 KiB
    __shared__ float smax[2][128];
    __shared__ int   scol[2][128];
    __shared__ float srmx[2][128];
    __shared__ float sc0v[2][128];
    __shared__ float ssum[2][128];

    int t = threadIdx.x, lane = t & 63, w = t >> 6;
    int wr = (w & 1) * 64;          // wave row offset
    int wc = (w >> 1) * 32;         // wave col offset

    // XCD swizzle (bijective, 512 % 8 == 0)
    int bid = blockIdx.x;
    int xcd = bid & 7;
    int idin = bid >> 3;
    int bx = (xcd << 3) | (idin >> 3);
    int by = idin & 7;
    int bm0 = bx * BM;
    int bn0 = by * BN;

    // staging slots: slot s -> row = s>>3, stored kchunk (s&7) holds global
    // kchunk (s&7)^(row&7).
    int tr = t >> 3, tc = t & 7;
    const u16* gA[4]; int lAoff[4];
    #pragma unroll
    for (int i = 0; i < 4; i++) {
        int row = tr + 32 * i;
        int kc = tc ^ (row & 7);
        gA[i] = hb + (size_t)(bm0 + row) * KDIM + kc * 8;
        lAoff[i] = (t + 256 * i) * 8;
    }
    const u16* gB[2]; int lBoff[2];
    #pragma unroll
    for (int i = 0; i < 2; i++) {
        int row = tr + 32 * i;
        int kc = tc ^ (row & 7);
        gB[i] = bb + (size_t)(bn0 + row) * KDIM + kc * 8;
        lBoff[i] = (t + 256 * i) * 8;
    }

    floatx4 acc[4][2] = {};
    int kq = lane >> 4, l7 = lane & 7, m = lane & 15;
    int swz0 = ((kq) ^ l7) * 8;
    int swz1 = ((4 + kq) ^ l7) * 8;
    int aro = (wr + m) * BK;        // fragment row base offsets within a buffer
    int bro = (wc + m) * BK;

    // ---- prologue: stage tile 0 into buf 0 --------------------------------
    #pragma unroll
    for (int i = 0; i < 4; i++) async_copy16(gA[i], &As[0][lAoff[i]]);
    #pragma unroll
    for (int i = 0; i < 2; i++) async_copy16(gB[i], &Bs[0][lBoff[i]]);
    #pragma unroll
    for (int i = 0; i < 4; i++) gA[i] += BK;
    #pragma unroll
    for (int i = 0; i < 2; i++) gB[i] += BK;
    __syncthreads();                 // drain tile-0 DMA

    // ---- main loop: one barrier per step ----------------------------------
    #pragma unroll
    for (int step = 0; step < NSTEP; ++step) {
        int cur = step & 1;
        if (step + 1 < NSTEP) {      // issue next tile first; flies under MFMA
            #pragma unroll
            for (int i = 0; i < 4; i++) {
                async_copy16(gA[i], &As[cur ^ 1][lAoff[i]]);
                gA[i] += BK;
            }
            #pragma unroll
            for (int i = 0; i < 2; i++) {
                async_copy16(gB[i], &Bs[cur ^ 1][lBoff[i]]);
                gB[i] += BK;
            }
        }
        const u16* paA = &As[cur][aro];
        const u16* paB = &Bs[cur][bro];
        #pragma unroll
        for (int s = 0; s < 2; s++) {
            int sw = s ? swz1 : swz0;
            shortx8 af[4], bf[2];
            #pragma unroll
            for (int i = 0; i < 4; i++) af[i] = *(const shortx8*)(paA + i * 16 * BK + sw);
            #pragma unroll
            for (int jj = 0; jj < 2; jj++) bf[jj] = *(const shortx8*)(paB + jj * 16 * BK + sw);
            #pragma unroll
            for (int i = 0; i < 4; i++)
                #pragma unroll
                for (int jj = 0; jj < 2; jj++)
                    acc[i][jj] = __builtin_amdgcn_mfma_f32_16x16x32_bf16(af[i], bf[jj], acc[i][jj], 0, 0, 0);
        }
        __syncthreads();             // all reads of buf done + next-tile DMA landed
    }

    // ---- epilogue: logits in-register, reduce 64 cols -> per-row partials --
    // C/D: col = lane&15 (=m), row = kq*4 + reg. Lane's 2 cols:
    int c0 = bn0 + wc + m, c1 = c0 + 16;
    float ps0 = psq[c0], ps1 = psq[c1];
    float inv0 = 0.5f / radii[c0], inv1 = 0.5f / radii[c1];
    int sl0 = slab[c0], sl1 = slab[c1];
    int slabz = slab[0];
    int ninit = ninit_p[0];
    int ch = w >> 1;                 // column half within block
    bool isL0 = (bn0 == 0) && (wc == 0) && (m == 0);

    #pragma unroll
    for (int i = 0; i < 4; i++) {
        #pragma unroll
        for (int r = 0; r < 4; r++) {
            int n = bm0 + wr + i * 16 + kq * 4 + r;
            float hsqn = hsq[n];
            int yv = y[n];
            int lab = (yv >= ninit) ? -1 : yv;
            float v0 = (2.0f * acc[i][0][r] - hsqn - ps0) * inv0;
            float v1 = (2.0f * acc[i][1][r] - hsqn - ps1) * inv1;
            if (isL0) l0arr[n] = v0;                 // logits[n][0]

            float bmax = v0; int bcol = c0;
            if (v1 > bmax) { bmax = v1; bcol = c1; } // tie keeps lower col
            float brm = -INFINITY;
            if (sl0 == lab) brm = v0;
            if (sl1 == lab && v1 > brm) brm = v1;
            float bc0 = -INFINITY;
            if (sl0 == slabz) bc0 = v0;
            if (sl1 == slabz && v1 > bc0) bc0 = v1;
            #pragma unroll
            for (int off = 1; off < 16; off <<= 1) {   // reduce over m (16 lanes)
                float ov = __shfl_xor(bmax, off); int oc = __shfl_xor(bcol, off);
                if (ov > bmax || (ov == bmax && oc < bcol)) { bmax = ov; bcol = oc; }
                float orv = __shfl_xor(brm, off); if (orv > brm) brm = orv;
                float oc0 = __shfl_xor(bc0, off); if (oc0 > bc0) bc0 = oc0;
            }
            float se = __expf(v0 - bmax) + __expf(v1 - bmax);
            #pragma unroll
            for (int off = 1; off < 16; off <<= 1) se += __shfl_xor(se, off);
            if (m == 0) {
                int rl = (w & 1) * 64 + i * 16 + kq * 4 + r;
                smax[ch][rl] = bmax; scol[ch][rl] = bcol;
                srmx[ch][rl] = brm;  sc0v[ch][rl] = bc0; ssum[ch][rl] = se;
            }
        }
    }
    __syncthreads();
    if (t < 128) {                    // merge the two 32-col halves, write
        int n = bm0 + t;
        size_t gi_ = (size_t)by * N_ROWS + n;
        float m0 = smax[0][t], m1 = smax[1][t];
        int i0 = scol[0][t], i1 = scol[1][t];
        float gm; int gi;
        if (m0 > m1 || (m0 == m1 && i0 < i1)) { gm = m0; gi = i0; }
        else { gm = m1; gi = i1; }
        pmax_g[gi_] = gm;
        pidx_g[gi_] = gi;
        prmax_g[gi_] = fmaxf(srmx[0][t], srmx[1][t]);
        pc0_g[gi_]  = fmaxf(sc0v[0][t], sc0v[1][t]);
        psum_g[gi_] = ssum[0][t] * __expf(m0 - gm) + ssum[1][t] * __expf(m1 - gm);
    }
}

// ---- kernel 3: combine 8 column-block partials per row -> loss, acc --------
__global__ __launch_bounds__(256) void combine(const float* __restrict__ pmax_g,
                                               const int* __restrict__ pidx_g,
                                               const float* __restrict__ prmax_g,
                                               const float* __restrict__ pc0_g,
                                               const float* __restrict__ psum_g,
                                               const float* __restrict__ l0arr,
                                               const int* __restrict__ y,
                                               const int* __restrict__ slab,
                                               const int* __restrict__ ninit_p,
                                               float* __restrict__ out) {
    int t = threadIdx.x, lane = t & 63, w = t >> 6;
    int n = blockIdx.x * 256 + t;

    float gm = -INFINITY; int gi = 0x7fffffff;
    float rm = -INFINITY, c0m = -INFINITY;
    float pm[8];
    #pragma unroll
    for (int cb = 0; cb < 8; cb++) {
        size_t idx = (size_t)cb * N_ROWS + n;
        float p = pmax_g[idx]; int pi = pidx_g[idx];
        pm[cb] = p;
        if (p > gm || (p == gm && pi < gi)) { gm = p; gi = pi; }
        rm = fmaxf(rm, prmax_g[idx]);
        c0m = fmaxf(c0m, pc0_g[idx]);
    }
    float den = 0.0f;
    #pragma unroll
    for (int cb = 0; cb < 8; cb++)
        den += psum_g[(size_t)cb * N_ROWS + n] * __expf(pm[cb] - gm);
    float lse = gm + __logf(den);

    int yv = y[n];
    int lab = (yv >= ninit_p[0]) ? -1 : yv;
    float nll, wgt;
    if (rm != -INFINITY) { nll = lse - rm; wgt = 1.0f; }
    else {                                   // all-(-inf) argmax -> col 0
        float l0 = l0arr[n];
        nll = lse - l0;
        wgt = (l0 == c0m) ? 1.0f : 0.0f;
    }
    int ypred = slab[gi];
    float li = nll * wgt * (1.0f / (float)N_ROWS);
    float ai = (ypred == lab) ? 1.0f : 0.0f;

    #pragma unroll
    for (int off = 32; off; off >>= 1) {
        li += __shfl_xor(li, off);
        ai += __shfl_xor(ai, off);
    }
    __shared__ float pl[4], pa_[4];
    if (lane == 0) { pl[w] = li; pa_[w] = ai; }
    __syncthreads();
    if (t == 0) {
        atomicAdd(&out[0], pl[0] + pl[1] + pl[2] + pl[3]);
        atomicAdd(&out[1], pa_[0] + pa_[1] + pa_[2] + pa_[3]);
    }
}

extern "C" void kernel_launch(void* const* d_in, const int* in_sizes, int n_in,
                              void* d_out, int out_size, void* d_ws, size_t ws_size,
                              hipStream_t stream) {
    const float* h      = (const float*)d_in[0];
    const float* protos = (const float*)d_in[1];
    const float* radii  = (const float*)d_in[2];
    const int*   y      = (const int*)d_in[3];
    const int*   slab   = (const int*)d_in[4];
    const int*   ninit  = (const int*)d_in[5];
    float* out = (float*)d_out;

    char* ws = (char*)d_ws;
    u16*   hb    = (u16*)(ws);                       // 16 MiB
    u16*   bb    = (u16*)(ws + 16777216);            // 1 MiB
    float* hsq   = (float*)(ws + 17825792);          // 32 KiB
    float* psq   = (float*)(ws + 17858560);          // 2 KiB
    float* pmax  = (float*)(ws + 17860608);          // 8*8192*4 = 256 KiB
    int*   pidx  = (int*)  (ws + 18122752);
    float* prmax = (float*)(ws + 18384896);
    float* pc0   = (float*)(ws + 18647040);
    float* psum  = (float*)(ws + 18909184);
    float* l0arr = (float*)(ws + 19171328);          // 32 KiB

    conv_hp<<<640, 256, 0, stream>>>(h, protos, hb, bb, hsq, psq, out);
    gemm_partials<<<512, 256, 0, stream>>>(hb, bb, hsq, psq, radii, y, slab, ninit,
                                           pmax, pidx, prmax, pc0, psum, l0arr);
    combine<<<N_ROWS / 256, 256, 0, stream>>>(pmax, pidx, prmax, pc0, psum,
                                              l0arr, y, slab, ninit, out);
}